// Round 8
// baseline (695.689 us; speedup 1.0000x reference)
//
#include <hip/hip_runtime.h>
#include <math.h>

typedef float v2 __attribute__((ext_vector_type(2)));

constexpr float CC   = 1.2f;
constexpr float SQC  = 1.09544511501033215f;      // sqrt(1.2)
constexpr float MAXN = (1.0f - 4e-3f) / SQC;      // geoopt projx maxnorm
constexpr float MINN = 1e-15f;

// ---------------- ws float offsets (transposed padded weights + constants) ----
constexpr int WTH1 = 0;        // [32][128]
constexpr int WTH2 = 4096;     // [80][128]
constexpr int WTH3 = 14336;    // [104][128]
constexpr int WTAH = 27648;    // [128][128]
constexpr int WTE1 = 44032;    // [32][128]
constexpr int WTE2 = 48128;    // [80][128]
constexpr int WTE3 = 58368;    // [104][128]
constexpr int EB1  = 71680;    // expmap0(bh1) padded 128
constexpr int EB2  = 71808;
constexpr int EB3  = 71936;
constexpr int EBA  = 72064;
constexpr int BE1  = 72192;    // be1 padded 128
constexpr int BE2  = 72320;
constexpr int BE3  = 72448;
constexpr int U1o  = 72576;    // Wae^T wte
constexpr int U2o  = 72704;    // Wae^T wth
constexpr int SCo  = 72832;    // c1,c2,y2h1,y2h2,y2h3,y2ah,EBW1,EBW2
constexpr int PART = 72864;    // 2048 blocks x 10 classifier partials

// ---------------- LDS float offsets (64-token half-row blocks) ----------------
constexpr int ASTR  = 65;      // ACT row stride
constexpr int L_ACT = 0;       // 128*65 = 8320
constexpr int L_ZH  = 8320;    // 10*64
constexpr int L_SCR = 8960;    // 12*64 scratch slots
constexpr int L_TOT = 9728;    // 38,912 B -> 4 blocks/CU (16 waves/CU)

// ---------------- v2 helpers ----------------
__device__ __forceinline__ v2 v2s(float s){ v2 r; r.x=s; r.y=s; return r; }
__device__ __forceinline__ v2 fmav(v2 a, v2 b, v2 c){ return __builtin_elementwise_fma(a,b,c); }
__device__ __forceinline__ v2 fma2(float w, v2 x, v2 a){ return __builtin_elementwise_fma(v2s(w),x,a); }
__device__ __forceinline__ v2 max0(v2 a){ v2 r; r.x=fmaxf(a.x,0.f); r.y=fmaxf(a.y,0.f); return r; }

// ---------------- scalar math ----------------
__device__ __forceinline__ float art_(float x){
  x = fminf(fmaxf(x, -0.9999999f), 0.9999999f);
  return 0.5f * __logf((1.0f + x) / (1.0f - x));
}
__device__ __forceinline__ float tanh_(float x){
  x = fminf(fmaxf(x, -15.0f), 15.0f);
  float e = __expf(2.0f * x);
  return (e - 1.0f) / (e + 1.0f);
}
__device__ __forceinline__ float wsum(float v){
#pragma unroll
  for(int i=32;i>0;i>>=1) v += __shfl_xor(v, i, 64);
  return v;
}
__device__ __forceinline__ float rtj(float v){   // sum over the 16 tj lanes
  v += __shfl_xor(v, 1, 64); v += __shfl_xor(v, 2, 64);
  v += __shfl_xor(v, 4, 64); v += __shfl_xor(v, 8, 64);
  return v;
}
__device__ __forceinline__ float lamv(float nv){
  float n = fmaxf(nv, MINN);
  return art_(SQC*n)/(SQC*n);
}
struct HS { float ca, cb, nv; };
__device__ __forceinline__ HS hyper_chain(float m2, float meb, float xn_in, float y2){
  float xn  = fmaxf(xn_in, MINN);
  float mxn = fmaxf(sqrtf(m2), MINN);
  float r   = art_(SQC*xn);
  float s   = tanh_(mxn/xn*r)/(mxn*SQC);
  float nr  = s*mxn;
  if(nr > MAXN){ s *= MAXN/nr; nr = MAXN; }
  float xy = s*meb, x2 = nr*nr;
  float den = fmaxf(1.f + 2.f*CC*xy + CC*CC*x2*y2, MINN);
  float A   = (1.f + 2.f*CC*xy + CC*y2)/den;
  float Bc  = (1.f - CC*x2)/den;
  float n3  = sqrtf(fmaxf(A*A*x2 + 2.f*A*Bc*xy + Bc*Bc*y2, 0.f));
  float rho = (n3 > MAXN) ? MAXN/n3 : 1.f;
  HS h; h.nv = fminf(n3, MAXN); h.ca = rho*A*s; h.cb = rho*Bc;
  return h;
}
struct TT { float tau, nf; };
__device__ __forceinline__ TT tail_relu(float rn2){
  float rn = fmaxf(sqrtf(rn2), MINN);
  float th = tanh_(SQC*rn);
  TT r; r.tau = th/(SQC*rn); r.nf = th/SQC;
  if(r.nf > MAXN){ r.tau *= MAXN/r.nf; r.nf = MAXN; }
  return r;
}
struct EX { float nh, scl; };
__device__ __forceinline__ EX exp0(float n2){
  float n0 = fmaxf(sqrtf(n2), MINN);
  float th = tanh_(SQC*n0);
  EX e; e.nh = th/SQC; e.scl = th/(SQC*n0);
  if(e.nh > MAXN){ e.scl *= MAXN/e.nh; e.nh = MAXN; }
  return e;
}
struct THW { float te, th2; };
__device__ __forceinline__ THW ahchain(float m2a, float mw1, float mw2, float meba,
                                       float xnh, float rr, float y2,
                                       float ebw1, float ebw2){
  float mxn = fmaxf(sqrtf(m2a), MINN);
  float s = tanh_(mxn/xnh*rr)/(mxn*SQC);
  float nr = s*mxn;
  if(nr > MAXN){ s *= MAXN/nr; nr = MAXN; }
  float xy = s*meba, x2 = nr*nr;
  float den = fmaxf(1.f + 2.f*CC*xy + CC*CC*x2*y2, MINN);
  float A = (1.f + 2.f*CC*xy + CC*y2)/den;
  float Bc = (1.f - CC*x2)/den;
  float n3 = sqrtf(fmaxf(A*A*x2 + 2.f*A*Bc*xy + Bc*Bc*y2, 0.f));
  float rho = (n3 > MAXN) ? MAXN/n3 : 1.f;
  float nv = fminf(n3, MAXN);
  float lr = lamv(nv)*rho;
  THW r; r.te = lr*(A*s*mw1 + Bc*ebw1); r.th2 = lr*(A*s*mw2 + Bc*ebw2);
  return r;
}
struct AG { float wge, g2; };
__device__ __forceinline__ AG attn(float d1, float d2, float thte, float thth,
                                   float rr, float xnh, float b_e, float b_h){
  float a_e = 0.5f*(d1 - thte) + b_e;
  float a_h = 0.5f*(thth - d2) + b_h;
  float mx = fmaxf(a_e, a_h);
  float ee = __expf(a_e - mx), eh = __expf(a_h - mx);
  float inv = 1.f/(ee + eh);
  AG r; r.wge = ee*inv;
  float wgh = eh*inv;
  float inner = wgh*rr;
  float scl2 = tanh_(inner)/(xnh*SQC);
  float nn = scl2*xnh;
  if(nn > MAXN){ scl2 *= MAXN/nn; nn = MAXN; }
  r.g2 = lamv(nn)*scl2;
  return r;
}

// ---------------- setup A: folded constants ----------------
__global__ void k_setup_a(const float* __restrict__ Wae, const float* __restrict__ bae,
                          const float* __restrict__ bh1, const float* __restrict__ bh2,
                          const float* __restrict__ bh3, const float* __restrict__ bah,
                          const float* __restrict__ Wte, const float* __restrict__ Wth,
                          const float* __restrict__ be1, const float* __restrict__ be2,
                          const float* __restrict__ be3, float* __restrict__ ws){
  const int tid = threadIdx.x;            // 256 threads, 1 block
  {
    const int which = tid >> 7, k = tid & 127;
    const float* wv = which ? Wth : Wte;
    float s = 0.f;
#pragma unroll 4
    for(int j=0;j<128;++j) s += Wae[j*128+k] * wv[j];
    ws[(which ? U2o : U1o) + k] = s;
  }
  if(tid < 128){
    ws[BE1+tid] = (tid < 80)  ? be1[tid] : 0.f;
    ws[BE2+tid] = (tid < 104) ? be2[tid] : 0.f;
    ws[BE3+tid] = be3[tid];
  }
  if(tid < 64){
    const int l = tid;
    float p1=0.f, p2=0.f;
    for(int j=l;j<128;j+=64){ p1 += bae[j]*Wte[j]; p2 += bae[j]*Wth[j]; }
    p1 = wsum(p1); p2 = wsum(p2);
    if(l==0){ ws[SCo+0]=p1; ws[SCo+1]=p2; }
    const float* bs[4] = {bh1,bh2,bh3,bah};
    const int dims[4]  = {80,104,128,128};
    const int offs[4]  = {EB1,EB2,EB3,EBA};
    for(int v=0;v<4;++v){
      const float* bp = bs[v]; const int D = dims[v];
      float q = 0.f;
      for(int j=l;j<D;j+=64) q += bp[j]*bp[j];
      q = wsum(q);
      float nb = fmaxf(sqrtf(q), MINN);
      float th = tanhf(fminf(fmaxf(SQC*nb,-15.f),15.f));
      float coef = th/(SQC*nb);
      float ne = th/SQC;
      if(ne > MAXN){ coef *= MAXN/ne; ne = MAXN; }
      for(int j=l;j<D;j+=64) ws[offs[v]+j] = coef*bp[j];
      for(int j=D+l;j<128;j+=64) ws[offs[v]+j] = 0.f;   // pad
      if(l==0) ws[SCo+2+v] = ne*ne;
      if(v==3){
        float e1=0.f, e2=0.f;
        for(int j=l;j<D;j+=64){ e1 += bp[j]*Wte[j]; e2 += bp[j]*Wth[j]; }
        e1 = wsum(e1)*coef; e2 = wsum(e2)*coef;
        if(l==0){ ws[SCo+6]=e1; ws[SCo+7]=e2; }
      }
    }
  }
}

// ---------------- setup B: transpose + pad weights into ws (k-major) --------
__global__ void k_trans(const float* __restrict__ Wh1, const float* __restrict__ Wh2,
                        const float* __restrict__ Wh3, const float* __restrict__ Wah,
                        const float* __restrict__ We1, const float* __restrict__ We2,
                        const float* __restrict__ We3, float* __restrict__ ws){
  const int blk = blockIdx.x, j = threadIdx.x;   // grid 560, block 128
  const float* W; int OUT, K, kk, dst;
  if(blk < 32)       { W=Wh1; OUT=80;  K=32;  kk=blk;      dst=WTH1; }
  else if(blk < 112) { W=Wh2; OUT=104; K=80;  kk=blk-32;   dst=WTH2; }
  else if(blk < 216) { W=Wh3; OUT=128; K=104; kk=blk-112;  dst=WTH3; }
  else if(blk < 344) { W=Wah; OUT=128; K=128; kk=blk-216;  dst=WTAH; }
  else if(blk < 376) { W=We1; OUT=80;  K=32;  kk=blk-344;  dst=WTE1; }
  else if(blk < 456) { W=We2; OUT=104; K=80;  kk=blk-376;  dst=WTE2; }
  else               { W=We3; OUT=128; K=104; kk=blk-456;  dst=WTE3; }
  ws[dst + kk*128 + j] = (j < OUT) ? W[j*K + kk] : 0.f;
}

// ---------------- finishing kernel: combine halves + classifier ----------------
__global__ void k_fin(const float* __restrict__ ws, const float* __restrict__ bf1,
                      const float* __restrict__ Wf2, const float* __restrict__ bf2,
                      float* __restrict__ out){
  const int r = blockIdx.x*64 + threadIdx.x;   // grid 16 x 64 = 1024 rows
  const float* p = ws + PART + (size_t)r*20;
  float f1[10];
#pragma unroll
  for(int i=0;i<10;++i)
    f1[i] = fmaxf((p[i] + p[10+i])*(1.f/128.f) + bf1[i], 0.f);
#pragma unroll
  for(int o=0;o<10;++o){
    float a = bf2[o];
#pragma unroll
    for(int k=0;k<10;++k) a = fmaf(Wf2[o*10+k], f1[k], a);
    out[r*10 + o] = a;
  }
}

// ---------------- GEMM inner: 8 feat x 4 tok (2 x v2) tile, pipelined --------
__device__ __forceinline__ void ld8(const float* __restrict__ p, float (&v)[8]){
  float4 a = *(const float4*)p, b = *(const float4*)(p+4);
  v[0]=a.x; v[1]=a.y; v[2]=a.z; v[3]=a.w; v[4]=b.x; v[5]=b.y; v[6]=b.z; v[7]=b.w;
}

template<int K, bool XG, bool XSQ>
__device__ __forceinline__ void gemm4(const float* __restrict__ wt,
                                      const float* __restrict__ xg,
                                      const float* __restrict__ ACT,
                                      int tj, int tt, v2 (&acc)[2][8], v2 (&xsq)[2]){
#pragma unroll
  for(int p=0;p<2;++p)
#pragma unroll
    for(int j=0;j<8;++j) acc[p][j] = v2s(0.f);
  const int wo = tj*8, xo = tt*4;
  constexpr int NC = K >> 1;           // 2-k chunks (all K even, NC even >= 2)
  float4 wA[4], wB[4], xA[2], xB[2];
  auto ld = [&](int ch, float4 (&w)[4], float4 (&xq)[2]){
    const int k0 = ch*2;
    w[0] = *(const float4*)(wt + k0*128 + wo);
    w[1] = *(const float4*)(wt + k0*128 + wo + 4);
    w[2] = *(const float4*)(wt + k0*128 + 128 + wo);
    w[3] = *(const float4*)(wt + k0*128 + 128 + wo + 4);
    if(XG){ xq[0] = *(const float4*)(xg + k0*128 + xo);
            xq[1] = *(const float4*)(xg + k0*128 + 128 + xo); }
    else  { xq[0] = *(const float4*)(ACT + k0*ASTR + xo);
            xq[1] = *(const float4*)(ACT + k0*ASTR + ASTR + xo); }
  };
  auto mth = [&](const float4 (&w)[4], const float4 (&xq)[2]){
#pragma unroll
    for(int kk=0;kk<2;++kk){
      const float4 xa = xq[kk];
      v2 xp0; xp0.x = xa.x; xp0.y = xa.y;
      v2 xp1; xp1.x = xa.z; xp1.y = xa.w;
      if(XSQ){ xsq[0] = fmav(xp0,xp0,xsq[0]); xsq[1] = fmav(xp1,xp1,xsq[1]); }
      const float4 wlo = w[kk*2], whi = w[kk*2+1];
      const float wv[8] = {wlo.x,wlo.y,wlo.z,wlo.w,whi.x,whi.y,whi.z,whi.w};
#pragma unroll
      for(int j=0;j<8;++j){
        acc[0][j] = fma2(wv[j], xp0, acc[0][j]);
        acc[1][j] = fma2(wv[j], xp1, acc[1][j]);
      }
    }
  };
  ld(0, wA, xA);
  for(int c=0; c<NC-2; c+=2){
    ld(c+1, wB, xB);
    mth(wA, xA);
    ld(c+2, wA, xA);
    mth(wB, xB);
  }
  ld(NC-1, wB, xB);
  mth(wA, xA);
  mth(wB, xB);
}

__device__ __forceinline__ void wACT(float* __restrict__ ACT, const v2 (&acc)[2][8],
                                     int tj, int tt){
#pragma unroll
  for(int j=0;j<8;++j){
    float4 a = {acc[0][j].x, acc[0][j].y, acc[1][j].x, acc[1][j].y};
    *(float4*)(ACT + (tj*8+j)*ASTR + tt*4) = a;
  }
}

// ---------------- main kernel: 1 block (256 thr) per 64-token half-row --------
// thread (tj,tt): features tj*8..+7 x tokens tt*4..+3 (2 v2 pairs).
__global__ __launch_bounds__(256, 4) void k_main(
    const float* __restrict__ x,
    const float* __restrict__ Wf1, const float* __restrict__ Wte,
    const float* __restrict__ bte, const float* __restrict__ Wth,
    const float* __restrict__ bth, float* __restrict__ ws){
  extern __shared__ float lds[];
  float* ACT = lds + L_ACT;
  float* ZH  = lds + L_ZH;
  float* SCR = lds + L_SCR;
  const int tid = threadIdx.x, tj = tid & 15, tt = tid >> 4;
  const int b = blockIdx.x, b2 = b >> 1, hf = b & 1;
  const int tok0 = tt*4;
  const bool isTok = tid < 64;
  const float* xg = x + (size_t)b2*4096 + hf*64;

  v2 acc[2][8];
  v2 xsq[2] = {v2s(0.f), v2s(0.f)};

  // persistent per-token state (token-thread registers, tid<64)
  float nf = 0.f, rr = 0.f, xnh = 1.f, thte = 0.f, thth = 0.f;

  // ================= H1: 32 -> 128(pad80), mob_relu =================
  {
    gemm4<32,true,true>(ws+WTH1, xg, ACT, tj, tt, acc, xsq);
    float ebv[8]; ld8(ws+EB1+tj*8, ebv);
    v2 sv[2]={v2s(0.f),v2s(0.f)}, ev[2]={v2s(0.f),v2s(0.f)};
#pragma unroll
    for(int p=0;p<2;++p)
#pragma unroll
      for(int j=0;j<8;++j){
        sv[p] = fmav(acc[p][j], acc[p][j], sv[p]);
        ev[p] = fma2(ebv[j], acc[p][j], ev[p]);
      }
    float s4[4]={sv[0].x,sv[0].y,sv[1].x,sv[1].y};
    float e4[4]={ev[0].x,ev[0].y,ev[1].x,ev[1].y};
    float q4[4]={xsq[0].x,xsq[0].y,xsq[1].x,xsq[1].y};
#pragma unroll
    for(int i=0;i<4;++i){
      float s=rtj(s4[i]), e=rtj(e4[i]);
      if(tj==0){ SCR[tok0+i]=s; SCR[64+tok0+i]=e; SCR[128+tok0+i]=q4[i]; }
    }
    __syncthreads();
    if(isTok){
      EX e0 = exp0(SCR[128+tid]);
      float scl0 = e0.scl;
      float m2 = SCR[tid]*scl0*scl0, meb = SCR[64+tid]*scl0;
      HS h = hyper_chain(m2, meb, e0.nh, ws[SCo+2]);
      SCR[tid] = h.ca*scl0; SCR[64+tid] = h.cb; SCR[128+tid] = lamv(h.nv);
    }
    __syncthreads();
    v2 cav[2],cbv[2],lmv[2];
#pragma unroll
    for(int p=0;p<2;++p){
      cav[p] = *(const v2*)(SCR+tok0+2*p);
      cbv[p] = *(const v2*)(SCR+64+tok0+2*p);
      lmv[p] = *(const v2*)(SCR+128+tok0+2*p);
    }
    v2 rs[2]={v2s(0.f),v2s(0.f)};
#pragma unroll
    for(int p=0;p<2;++p)
#pragma unroll
      for(int j=0;j<8;++j){
        v2 v = max0(lmv[p]*fmav(cav[p], acc[p][j], cbv[p]*v2s(ebv[j])));
        acc[p][j]=v; rs[p]=fmav(v,v,rs[p]);
      }
    float r4[4]={rs[0].x,rs[0].y,rs[1].x,rs[1].y};
#pragma unroll
    for(int i=0;i<4;++i){
      float s=rtj(r4[i]);
      if(tj==0) SCR[192+tok0+i]=s;
    }
    __syncthreads();
    if(isTok){ TT tr = tail_relu(SCR[192+tid]); nf = tr.nf; SCR[192+tid]=tr.tau; }
    __syncthreads();
    v2 tau[2];
#pragma unroll
    for(int p=0;p<2;++p) tau[p] = *(const v2*)(SCR+192+tok0+2*p);
#pragma unroll
    for(int p=0;p<2;++p)
#pragma unroll
      for(int j=0;j<8;++j) acc[p][j] = acc[p][j]*tau[p];
    wACT(ACT, acc, tj, tt);
    __syncthreads();
  }

  // ================= H2: 80 -> 128(pad104), mob_relu =================
  {
    gemm4<80,false,false>(ws+WTH2, nullptr, ACT, tj, tt, acc, xsq);
    float ebv[8]; ld8(ws+EB2+tj*8, ebv);
    v2 sv[2]={v2s(0.f),v2s(0.f)}, ev[2]={v2s(0.f),v2s(0.f)};
#pragma unroll
    for(int p=0;p<2;++p)
#pragma unroll
      for(int j=0;j<8;++j){
        sv[p] = fmav(acc[p][j], acc[p][j], sv[p]);
        ev[p] = fma2(ebv[j], acc[p][j], ev[p]);
      }
    float s4[4]={sv[0].x,sv[0].y,sv[1].x,sv[1].y};
    float e4[4]={ev[0].x,ev[0].y,ev[1].x,ev[1].y};
#pragma unroll
    for(int i=0;i<4;++i){
      float s=rtj(s4[i]), e=rtj(e4[i]);
      if(tj==0){ SCR[tok0+i]=s; SCR[64+tok0+i]=e; }
    }
    __syncthreads();
    if(isTok){
      HS h = hyper_chain(SCR[tid], SCR[64+tid], nf, ws[SCo+3]);
      SCR[tid]=h.ca; SCR[64+tid]=h.cb; SCR[128+tid]=lamv(h.nv);
    }
    __syncthreads();
    v2 cav[2],cbv[2],lmv[2];
#pragma unroll
    for(int p=0;p<2;++p){
      cav[p] = *(const v2*)(SCR+tok0+2*p);
      cbv[p] = *(const v2*)(SCR+64+tok0+2*p);
      lmv[p] = *(const v2*)(SCR+128+tok0+2*p);
    }
    v2 rs[2]={v2s(0.f),v2s(0.f)};
#pragma unroll
    for(int p=0;p<2;++p)
#pragma unroll
      for(int j=0;j<8;++j){
        v2 v = max0(lmv[p]*fmav(cav[p], acc[p][j], cbv[p]*v2s(ebv[j])));
        acc[p][j]=v; rs[p]=fmav(v,v,rs[p]);
      }
    float r4[4]={rs[0].x,rs[0].y,rs[1].x,rs[1].y};
#pragma unroll
    for(int i=0;i<4;++i){
      float s=rtj(r4[i]);
      if(tj==0) SCR[192+tok0+i]=s;
    }
    __syncthreads();
    if(isTok){ TT tr = tail_relu(SCR[192+tid]); nf = tr.nf; SCR[192+tid]=tr.tau; }
    __syncthreads();
    v2 tau[2];
#pragma unroll
    for(int p=0;p<2;++p) tau[p] = *(const v2*)(SCR+192+tok0+2*p);
#pragma unroll
    for(int p=0;p<2;++p)
#pragma unroll
      for(int j=0;j<8;++j) acc[p][j] = acc[p][j]*tau[p];
    wACT(ACT, acc, tj, tt);
    __syncthreads();
  }

  // ================= H3: 104 -> 128, p_linear only (out_h) =================
  {
    gemm4<104,false,false>(ws+WTH3, nullptr, ACT, tj, tt, acc, xsq);
    float ebv[8]; ld8(ws+EB3+tj*8, ebv);
    v2 sv[2]={v2s(0.f),v2s(0.f)}, ev[2]={v2s(0.f),v2s(0.f)};
#pragma unroll
    for(int p=0;p<2;++p)
#pragma unroll
      for(int j=0;j<8;++j){
        sv[p] = fmav(acc[p][j], acc[p][j], sv[p]);
        ev[p] = fma2(ebv[j], acc[p][j], ev[p]);
      }
    float s4[4]={sv[0].x,sv[0].y,sv[1].x,sv[1].y};
    float e4[4]={ev[0].x,ev[0].y,ev[1].x,ev[1].y};
#pragma unroll
    for(int i=0;i<4;++i){
      float s=rtj(s4[i]), e=rtj(e4[i]);
      if(tj==0){ SCR[tok0+i]=s; SCR[64+tok0+i]=e; }
    }
    __syncthreads();
    if(isTok){
      HS h = hyper_chain(SCR[tid], SCR[64+tid], nf, ws[SCo+4]);
      xnh = fmaxf(h.nv, MINN);
      rr  = art_(SQC*xnh);
      SCR[tid]=h.ca; SCR[64+tid]=h.cb;
    }
    __syncthreads();
    v2 cav[2],cbv[2];
#pragma unroll
    for(int p=0;p<2;++p){
      cav[p] = *(const v2*)(SCR+tok0+2*p);
      cbv[p] = *(const v2*)(SCR+64+tok0+2*p);
    }
#pragma unroll
    for(int p=0;p<2;++p)
#pragma unroll
      for(int j=0;j<8;++j) acc[p][j] = fmav(cav[p], acc[p][j], cbv[p]*v2s(ebv[j]));
    wACT(ACT, acc, tj, tt);
    // zh[ic][t] = Wf1[ic,128+j] . out_h  (classifier fold)
#pragma unroll
    for(int ic=0;ic<10;++ic){
      float wf[8]; ld8(Wf1 + ic*256 + 128 + tj*8, wf);
      v2 zs[2]={v2s(0.f),v2s(0.f)};
#pragma unroll
      for(int p=0;p<2;++p)
#pragma unroll
        for(int j=0;j<8;++j) zs[p] = fma2(wf[j], acc[p][j], zs[p]);
      float z4[4]={zs[0].x,zs[0].y,zs[1].x,zs[1].y};
#pragma unroll
      for(int i=0;i<4;++i){
        float s=rtj(z4[i]);
        if(tj==0) ZH[ic*64 + tok0 + i] = s;
      }
    }
    __syncthreads();
  }

  // ================= Wah pass: 4 reductions of mx = Wah . out_h =============
  {
    gemm4<128,false,false>(ws+WTAH, nullptr, ACT, tj, tt, acc, xsq);
    float w1v[8], w2v[8], eav[8];
    ld8(Wte + tj*8, w1v); ld8(Wth + tj*8, w2v); ld8(ws+EBA+tj*8, eav);
    v2 a0[2]={v2s(0.f),v2s(0.f)}, a1[2]={v2s(0.f),v2s(0.f)};
    v2 a2[2]={v2s(0.f),v2s(0.f)}, a3[2]={v2s(0.f),v2s(0.f)};
#pragma unroll
    for(int p=0;p<2;++p)
#pragma unroll
      for(int j=0;j<8;++j){
        v2 m = acc[p][j];
        a0[p] = fmav(m,m,a0[p]);
        a1[p] = fma2(w1v[j],m,a1[p]);
        a2[p] = fma2(w2v[j],m,a2[p]);
        a3[p] = fma2(eav[j],m,a3[p]);
      }
    float t0[4]={a0[0].x,a0[0].y,a0[1].x,a0[1].y};
    float t1[4]={a1[0].x,a1[0].y,a1[1].x,a1[1].y};
    float t2[4]={a2[0].x,a2[0].y,a2[1].x,a2[1].y};
    float t3[4]={a3[0].x,a3[0].y,a3[1].x,a3[1].y};
#pragma unroll
    for(int i=0;i<4;++i){
      float s0=rtj(t0[i]), s1=rtj(t1[i]), s2=rtj(t2[i]), s3=rtj(t3[i]);
      if(tj==0){ SCR[tok0+i]=s0; SCR[64+tok0+i]=s1; SCR[128+tok0+i]=s2; SCR[192+tok0+i]=s3; }
    }
    __syncthreads();
    if(isTok){
      THW a = ahchain(SCR[tid], SCR[64+tid], SCR[128+tid], SCR[192+tid],
                      xnh, rr, ws[SCo+5], ws[SCo+6], ws[SCo+7]);
      thte = a.te; thth = a.th2;
    }
  }

  // ================= E1: relu(We1 x + be1) =================
  {
    gemm4<32,true,false>(ws+WTE1, xg, ACT, tj, tt, acc, xsq);
    float bev[8]; ld8(ws+BE1+tj*8, bev);
#pragma unroll
    for(int p=0;p<2;++p)
#pragma unroll
      for(int j=0;j<8;++j) acc[p][j] = max0(acc[p][j] + v2s(bev[j]));
    __syncthreads();            // Wah gemm reads of ACT done before overwrite
    wACT(ACT, acc, tj, tt);
    __syncthreads();
  }
  // ================= E2 =================
  {
    gemm4<80,false,false>(ws+WTE2, nullptr, ACT, tj, tt, acc, xsq);
    float bev[8]; ld8(ws+BE2+tj*8, bev);
#pragma unroll
    for(int p=0;p<2;++p)
#pragma unroll
      for(int j=0;j<8;++j) acc[p][j] = max0(acc[p][j] + v2s(bev[j]));
    __syncthreads();            // all E2 reads of ACT done before overwrite
    wACT(ACT, acc, tj, tt);
    __syncthreads();
  }
  // ======== E3: out_e (in regs) -> d1,d2, ze; attention; partials ========
  {
    gemm4<104,false,false>(ws+WTE3, nullptr, ACT, tj, tt, acc, xsq);
    float bev[8], u1v[8], u2v[8];
    ld8(ws+BE3+tj*8, bev); ld8(ws+U1o+tj*8, u1v); ld8(ws+U2o+tj*8, u2v);
    v2 s1v[2]={v2s(0.f),v2s(0.f)}, s2v[2]={v2s(0.f),v2s(0.f)};
#pragma unroll
    for(int p=0;p<2;++p)
#pragma unroll
      for(int j=0;j<8;++j){
        v2 v = max0(acc[p][j] + v2s(bev[j]));
        acc[p][j] = v;
        s1v[p] = fma2(u1v[j],v,s1v[p]);
        s2v[p] = fma2(u2v[j],v,s2v[p]);
      }
    float d14[4]={s1v[0].x,s1v[0].y,s1v[1].x,s1v[1].y};
    float d24[4]={s2v[0].x,s2v[0].y,s2v[1].x,s2v[1].y};
#pragma unroll
    for(int i=0;i<4;++i){
      float s1=rtj(d14[i]), s2=rtj(d24[i]);
      if(tj==0){ SCR[tok0+i]=s1; SCR[64+tok0+i]=s2; }
    }
#pragma unroll
    for(int ic=0;ic<10;++ic){
      float wf[8]; ld8(Wf1 + ic*256 + tj*8, wf);
      v2 zs[2]={v2s(0.f),v2s(0.f)};
#pragma unroll
      for(int p=0;p<2;++p)
#pragma unroll
        for(int j=0;j<8;++j) zs[p] = fma2(wf[j], acc[p][j], zs[p]);
      float z4[4]={zs[0].x,zs[0].y,zs[1].x,zs[1].y};
#pragma unroll
      for(int i=0;i<4;++i){
        float s=rtj(z4[i]);
        if(tj==0) SCR[(2+ic)*64 + tok0 + i] = s;
      }
    }
    __syncthreads();
    if(isTok){
      float d1 = SCR[tid] + ws[SCo+0];
      float d2 = SCR[64+tid] + ws[SCo+1];
      AG g = attn(d1, d2, thte, thth, rr, xnh, bte[0], bth[0]);
      float pv[10];
#pragma unroll
      for(int ic=0;ic<10;++ic){
        float p = fmaf(g.wge, SCR[(2+ic)*64+tid], g.g2 * ZH[ic*64+tid]);
        pv[ic] = wsum(p);           // sum over this block's 64 tokens
      }
      if(tid == 0){
#pragma unroll
        for(int ic=0;ic<10;++ic) ws[PART + (size_t)b*10 + ic] = pv[ic];
      }
    }
  }
}

extern "C" void kernel_launch(void* const* d_in, const int* in_sizes, int n_in,
                              void* d_out, int out_size, void* d_ws, size_t ws_size,
                              hipStream_t stream){
  (void)in_sizes; (void)n_in; (void)out_size; (void)ws_size;
  const float* x   = (const float*)d_in[0];
  const float* We1 = (const float*)d_in[1];
  const float* be1 = (const float*)d_in[2];
  const float* We2 = (const float*)d_in[3];
  const float* be2 = (const float*)d_in[4];
  const float* We3 = (const float*)d_in[5];
  const float* be3 = (const float*)d_in[6];
  const float* Wh1 = (const float*)d_in[7];
  const float* bh1 = (const float*)d_in[8];
  const float* Wh2 = (const float*)d_in[9];
  const float* bh2 = (const float*)d_in[10];
  const float* Wh3 = (const float*)d_in[11];
  const float* bh3 = (const float*)d_in[12];
  const float* Wae = (const float*)d_in[13];
  const float* bae = (const float*)d_in[14];
  const float* Wah = (const float*)d_in[15];
  const float* bah = (const float*)d_in[16];
  const float* Wte = (const float*)d_in[17];
  const float* bte = (const float*)d_in[18];
  const float* Wth = (const float*)d_in[19];
  const float* bth = (const float*)d_in[20];
  const float* Wf1 = (const float*)d_in[21];
  const float* bf1 = (const float*)d_in[22];
  const float* Wf2 = (const float*)d_in[23];
  const float* bf2 = (const float*)d_in[24];
  float* ws  = (float*)d_ws;
  float* out = (float*)d_out;

  hipLaunchKernelGGL(k_setup_a, dim3(1), dim3(256), 0, stream,
                     Wae, bae, bh1, bh2, bh3, bah, Wte, Wth, be1, be2, be3, ws);
  hipLaunchKernelGGL(k_trans, dim3(560), dim3(128), 0, stream,
                     Wh1, Wh2, Wh3, Wah, We1, We2, We3, ws);

  const int smem = L_TOT * 4;   // 38,912 B -> 4 blocks/CU
  hipLaunchKernelGGL(k_main, dim3(2048), dim3(256), smem, stream,
                     x, Wf1, Wte, bte, Wth, bth, ws);

  hipLaunchKernelGGL(k_fin, dim3(16), dim3(64), 0, stream,
                     ws, bf1, Wf2, bf2, out);
}